// Round 8
// baseline (121.582 us; speedup 1.0000x reference)
//
#include <hip/hip_runtime.h>
#include <hip/hip_bf16.h>

#define BB 16
#define TT 2048
#define DIMC 512
#define HEADH 64

typedef __attribute__((ext_vector_type(8))) short short8v;   // 8 bf16 (4 VGPRs)
typedef __attribute__((ext_vector_type(4))) float f32x4;     // MFMA C/D

static __device__ __forceinline__ unsigned short f2bf(float f) {
    __hip_bfloat16 h = __float2bfloat16(f);          // RNE, native path
    unsigned short u;
    __builtin_memcpy(&u, &h, 2);
    return u;
}
static __device__ __forceinline__ unsigned int packbf(float lo, float hi) {
    float2 f2; f2.x = lo; f2.y = hi;
    __hip_bfloat162 h2 = __float22bfloat162_rn(f2);
    unsigned int u;
    __builtin_memcpy(&u, &h2, 4);
    return u;
}
// raw v_exp_f32 (input in log2 domain); ocml exp2f adds range handling we
// don't need (args <= 0; sub-denormal results contribute 0 to softmax)
#define EXP2R __builtin_amdgcn_exp2f
// async global->LDS, 16B per lane; LDS dest = base + lane*16 (linear)
static __device__ __forceinline__ void async_copy16(void* lds, const void* g) {
    __builtin_amdgcn_global_load_lds(
        (const __attribute__((address_space(1))) unsigned char*)g,
        (__attribute__((address_space(3))) unsigned char*)lds, 16, 0, 0);
}

union bfrag {
    unsigned int u[4];
    short8v v;
};

// ---------------- Kernel 0: W f32 -> bf16, concat [q|k|v] rows -------------
__global__ __launch_bounds__(256) void wcvt_kernel(
    const float* __restrict__ Wq, const float* __restrict__ Wk,
    const float* __restrict__ Wv, unsigned short* __restrict__ wb)
{
    const int idx = blockIdx.x * 256 + threadIdx.x;   // 12288 threads x 8 elems
    const int e   = idx << 3;
    const int row = e >> 9, col = e & 511;
    const float* src = (row < 64) ? Wq : (row < 128) ? Wk : Wv;
    const float* p = src + (size_t)(row & 63) * DIMC + col;
    float4 a = *(const float4*)p;
    float4 b = *(const float4*)(p + 4);
    uint4 o;
    o.x = packbf(a.x, a.y); o.y = packbf(a.z, a.w);
    o.z = packbf(b.x, b.y); o.w = packbf(b.z, b.w);
    *(uint4*)(wb + e) = o;
}

// ---------------- Kernel A: MFMA QKV projection + rotary -------------------
// C^T form: C[h][t] = W(192x512) . x^T, mfma_f32_16x16x32_bf16.
// Block = 3 waves, wave w = matrix (0=q,1=k,2=v). Wave tile: 16 t x 64 h.
// Round 8: t-tile 16 -> grid 2048 -> up to 24 waves/CU (75% occ). qkv was
// pure latency-bound at 3 waves/SIMD (r7: MfmaUtil 4.2, VALU 7, HBM 8%);
// TLP is the lever, not ILP (r7's explicit prefetch lost vs r4's plain loop).
__global__ __launch_bounds__(192) void qkv_mfma_kernel(
    const float* __restrict__ x,
    const unsigned short* __restrict__ wb,
    const float* __restrict__ fxr, const float* __restrict__ fxi,
    const float* __restrict__ fyr, const float* __restrict__ fyi,
    unsigned short* __restrict__ qo, unsigned short* __restrict__ ko,
    unsigned short* __restrict__ vt)
{
    const int tid = threadIdx.x;
    const int w   = tid >> 6;          // matrix: 0=q, 1=k, 2=v
    const int l   = tid & 63;
    const int q   = l & 15;
    const int g   = l >> 4;
    const int t0  = blockIdx.x << 4;   // 16 t-rows per block (global over B*T)

    f32x4 acc[4];
    #pragma unroll
    for (int ht = 0; ht < 4; ++ht) acc[ht] = (f32x4){0.f, 0.f, 0.f, 0.f};

    const unsigned short* wrow = wb + ((size_t)w * 64 + q) * DIMC + 8 * g;
    const float* xr0 = x + (size_t)(t0 + q) * DIMC + 8 * g;

    #pragma unroll 4
    for (int k0 = 0; k0 < DIMC; k0 += 32) {
        float4 a0 = *(const float4*)(xr0 + k0);
        float4 b0 = *(const float4*)(xr0 + k0 + 4);
        bfrag x0;
        x0.u[0] = packbf(a0.x, a0.y); x0.u[1] = packbf(a0.z, a0.w);
        x0.u[2] = packbf(b0.x, b0.y); x0.u[3] = packbf(b0.z, b0.w);

        short8v wf0 = *(const short8v*)(wrow + k0);
        short8v wf1 = *(const short8v*)(wrow + 16 * DIMC + k0);
        short8v wf2 = *(const short8v*)(wrow + 32 * DIMC + k0);
        short8v wf3 = *(const short8v*)(wrow + 48 * DIMC + k0);

        acc[0] = __builtin_amdgcn_mfma_f32_16x16x32_bf16(wf0, x0.v, acc[0], 0, 0, 0);
        acc[1] = __builtin_amdgcn_mfma_f32_16x16x32_bf16(wf1, x0.v, acc[1], 0, 0, 0);
        acc[2] = __builtin_amdgcn_mfma_f32_16x16x32_bf16(wf2, x0.v, acc[2], 0, 0, 0);
        acc[3] = __builtin_amdgcn_mfma_f32_16x16x32_bf16(wf3, x0.v, acc[3], 0, 0, 0);
    }

    const float qscale = 1.4426950408889634f / 22.627416997969522f; // log2e/sqrt(512)
    const int trow = t0 + q;
    const int tl   = trow & (TT - 1);
    if (w == 2) {
        const int b = trow >> 11;
        #pragma unroll
        for (int ht = 0; ht < 4; ++ht) {
            const int d = 16 * ht + 4 * g;
            #pragma unroll
            for (int r = 0; r < 4; ++r)
                vt[((size_t)(b * HEADH) + d + r) * TT + tl] = f2bf(acc[ht][r]);
        }
    } else {
        const float sc = (w == 0) ? qscale : 1.f;
        unsigned short* dst = ((w == 0) ? qo : ko) + (size_t)trow * HEADH;
        #pragma unroll
        for (int ht = 0; ht < 4; ++ht) {
            const int hbase = 16 * ht + 4 * g;
            const int half  = hbase >> 5;
            const float* frt = half ? fyr : fxr;
            const float* fit = half ? fyi : fxi;
            const int pi0 = (hbase & 31) >> 1;
            float fr0 = frt[tl * 16 + pi0],     fi0 = fit[tl * 16 + pi0];
            float fr1 = frt[tl * 16 + pi0 + 1], fi1 = fit[tl * 16 + pi0 + 1];
            float e0 = acc[ht][0] * fr0 - acc[ht][1] * fi0;
            float e1 = acc[ht][0] * fi0 + acc[ht][1] * fr0;
            float e2 = acc[ht][2] * fr1 - acc[ht][3] * fi1;
            float e3 = acc[ht][2] * fi1 + acc[ht][3] * fr1;
            uint2 ow;
            ow.x = packbf(e0 * sc, e1 * sc);
            ow.y = packbf(e2 * sc, e3 * sc);
            *(uint2*)(dst + hbase) = ow;
        }
    }
}

// ---------------- Kernel B: MFMA flash attention, q-split + LDS staging -----
// Block = 4 waves x 16 q-rows (q-tile 64). Full KV sweep, tiles of 64.
// K tile [64 kv][64 d] and V^T tile [64 d][64 t] staged bf16 in LDS via
// global_load_lds (16B/lane), double-buffered. XOR-swizzle slot = c16^(row&7)
// applied by PRE-SWIZZLING the per-lane global source (linear LDS dest);
// reads apply the same XOR -> conflict-free b128.
// Round 8: exp2f -> raw v_exp_f32 (EXP2R); r7 VALUBusy 45% implicated ocml
// exp2f expansion (~16 calls/iter on the critical softmax path).
__global__ __launch_bounds__(256, 2) void attn_mfma_kernel(
    const unsigned short* __restrict__ qws,   // [b][t][64] bf16, pre-scaled
    const unsigned short* __restrict__ kws,   // [b][t][64] bf16
    const unsigned short* __restrict__ vtw,   // [b][d][t]  bf16 (V^T)
    float* __restrict__ out)
{
    __shared__ unsigned char smem[40960];     // K dbuf 16K | V dbuf 16K | plds 8K

    const int tid = threadIdx.x;
    const int w   = tid >> 6;                 // wave -> q-subtile
    const int l   = tid & 63;
    const int q   = l & 15;
    const int g   = l >> 4;
    const int b   = blockIdx.x >> 5;
    const int q0  = (blockIdx.x & 31) << 6;   // 64 q-rows per block
    const int qw  = q0 + 16 * w;              // this wave's q base
    const int rx  = q & 7;                    // read-side swizzle
    const int swz = (q & 7) << 2;             // plds swizzle (verified r2-r7)

    const int rl = l >> 3;
    const int sl = (l & 7) ^ rl;              // involution pre-swizzle

    unsigned int* pldsw = (unsigned int*)(smem + 32768 + (w << 11));

    const unsigned short* kbase = kws + (size_t)b * TT * HEADH;
    const unsigned short* vbase = vtw + (size_t)b * HEADH * TT;

    const unsigned short* ksrc0 = kbase + (size_t)(16 * w + rl) * HEADH + 8 * sl;
    const unsigned short* ksrc1 = kbase + (size_t)(16 * w + 8 + rl) * HEADH + 8 * sl;
    const unsigned short* vsrc0 = vbase + (size_t)(16 * w + rl) * TT + 8 * sl;
    const unsigned short* vsrc1 = vbase + (size_t)(16 * w + 8 + rl) * TT + 8 * sl;

#define STAGE_TILE(bufsel, kv)  do {                                          \
        unsigned char* kd = smem + (bufsel) * 8192 + (w << 11);               \
        unsigned char* vd = smem + 16384 + (bufsel) * 8192 + (w << 11);       \
        async_copy16(kd,        ksrc0 + (size_t)(kv) * HEADH);                \
        async_copy16(kd + 1024, ksrc1 + (size_t)(kv) * HEADH);                \
        async_copy16(vd,        vsrc0 + (kv));                                \
        async_copy16(vd + 1024, vsrc1 + (kv));                                \
    } while (0)

    short8v qf0, qf1;
    {
        const unsigned short* qp = qws + ((size_t)(b * TT + qw + q)) * HEADH + 8 * g;
        qf0 = *(const short8v*)(qp);
        qf1 = *(const short8v*)(qp + 32);
    }

    f32x4 oacc[4];
    #pragma unroll
    for (int mt = 0; mt < 4; ++mt) oacc[mt] = (f32x4){0.f, 0.f, 0.f, 0.f};
    float m = -1e30f, lsum = 0.f;

    STAGE_TILE(0, 0);
    __syncthreads();                          // tile 0 resident

    int cur = 0;
    for (int it = 0; it < 32; ++it) {
        if (it < 31) STAGE_TILE(cur ^ 1, (it + 1) << 6);

        const unsigned char* kb = smem + cur * 8192;
        const unsigned char* vb = smem + 16384 + cur * 8192;

        // ---- QK^T from LDS ----
        f32x4 sacc[4];
        #pragma unroll
        for (int n = 0; n < 4; ++n) {
            const int r = 16 * n + q;
            const short8v k0 = *(const short8v*)(kb + r * 128 + ((g ^ rx) << 4));
            const short8v k1 = *(const short8v*)(kb + r * 128 + (((4 + g) ^ rx) << 4));
            f32x4 z = (f32x4){0.f, 0.f, 0.f, 0.f};
            z = __builtin_amdgcn_mfma_f32_16x16x32_bf16(k0, qf0, z, 0, 0, 0);
            z = __builtin_amdgcn_mfma_f32_16x16x32_bf16(k1, qf1, z, 0, 0, 0);
            sacc[n] = z;
        }

        // ---- online softmax (lane owns q-row qw + (l&15)) ----
        float cmax = sacc[0][0];
        #pragma unroll
        for (int n = 0; n < 4; ++n)
            #pragma unroll
            for (int r = 0; r < 4; ++r) cmax = fmaxf(cmax, sacc[n][r]);
        cmax = fmaxf(cmax, __shfl_xor(cmax, 16));
        cmax = fmaxf(cmax, __shfl_xor(cmax, 32));
        const float mnew = fmaxf(m, cmax);

        float p[4][4];
        float psum = 0.f;
        #pragma unroll
        for (int n = 0; n < 4; ++n)
            #pragma unroll
            for (int r = 0; r < 4; ++r) {
                p[n][r] = EXP2R(sacc[n][r] - mnew);   // raw v_exp_f32
                psum += p[n][r];
            }
        psum += __shfl_xor(psum, 16);
        psum += __shfl_xor(psum, 32);

        const float sc = EXP2R(m - mnew);
        if (__any(cmax > m)) {
            #pragma unroll
            for (int mt = 0; mt < 4; ++mt)
                #pragma unroll
                for (int r = 0; r < 4; ++r) oacc[mt][r] *= sc;
        }
        lsum = lsum * sc + psum;
        m = mnew;

        // ---- P^T -> bf16 -> per-wave swizzled LDS ----
        #pragma unroll
        for (int n = 0; n < 4; ++n) {
            uint2 wv;
            wv.x = packbf(p[n][0], p[n][1]);
            wv.y = packbf(p[n][2], p[n][3]);
            *(uint2*)&pldsw[q * 32 + ((8 * n + 2 * g) ^ swz)] = wv;
        }

        // ---- PV: out^T += V^T . P^T (V from LDS) ----
        #pragma unroll
        for (int s = 0; s < 2; ++s) {
            const short8v pb = *(const short8v*)&pldsw[q * 32 + ((16 * s + 4 * g) ^ swz)];
            #pragma unroll
            for (int mt = 0; mt < 4; ++mt) {
                const int d = 16 * mt + q;
                const short8v vfr = *(const short8v*)(vb + d * 128 + ((((s << 2) + g) ^ rx) << 4));
                oacc[mt] = __builtin_amdgcn_mfma_f32_16x16x32_bf16(vfr, pb, oacc[mt], 0, 0, 0);
            }
        }

        __syncthreads();                      // nxt resident; cur reads done
        cur ^= 1;
    }

    // ---- normalize + store: oacc[mt][r] = out[qw+q][16mt+4g+r] ----
    const float inv = 1.f / lsum;
    float* op = out + ((size_t)(b * TT + qw + q)) * HEADH;
    #pragma unroll
    for (int mt = 0; mt < 4; ++mt) {
        float4 v4 = make_float4(oacc[mt][0] * inv, oacc[mt][1] * inv,
                                oacc[mt][2] * inv, oacc[mt][3] * inv);
        *(float4*)(op + 16 * mt + 4 * g) = v4;
    }
#undef STAGE_TILE
}

extern "C" void kernel_launch(void* const* d_in, const int* in_sizes, int n_in,
                              void* d_out, int out_size, void* d_ws, size_t ws_size,
                              hipStream_t stream)
{
    const float* x   = (const float*)d_in[0];
    const float* Wq  = (const float*)d_in[1];
    const float* Wk  = (const float*)d_in[2];
    const float* Wv  = (const float*)d_in[3];
    const float* fxr = (const float*)d_in[4];
    const float* fxi = (const float*)d_in[5];
    const float* fyr = (const float*)d_in[6];
    const float* fyi = (const float*)d_in[7];
    float* out = (float*)d_out;

    unsigned short* qo = (unsigned short*)d_ws;                  // 4 MB
    unsigned short* ko = qo + (size_t)BB * TT * HEADH;           // 4 MB
    unsigned short* vt = ko + (size_t)BB * TT * HEADH;           // 4 MB
    unsigned short* wb = vt + (size_t)BB * TT * HEADH;           // 192 KB

    wcvt_kernel<<<48, 256, 0, stream>>>(Wq, Wk, Wv, wb);
    qkv_mfma_kernel<<<(BB * TT) / 16, 192, 0, stream>>>(x, wb, fxr, fxi, fyr, fyi,
                                                        qo, ko, vt);
    attn_mfma_kernel<<<BB * 32, 256, 0, stream>>>(qo, ko, vt, out);
}

// Round 9
// 71.737 us; speedup vs baseline: 1.6948x; 1.6948x over previous
//
#include <hip/hip_runtime.h>
#include <hip/hip_bf16.h>

#define BB 16
#define TT 2048
#define DIMC 512
#define HEADH 64

typedef __attribute__((ext_vector_type(8))) short short8v;   // 8 bf16 (4 VGPRs)
typedef __attribute__((ext_vector_type(4))) float f32x4;     // MFMA C/D

static __device__ __forceinline__ unsigned short f2bf(float f) {
    __hip_bfloat16 h = __float2bfloat16(f);          // RNE, native path
    unsigned short u;
    __builtin_memcpy(&u, &h, 2);
    return u;
}
static __device__ __forceinline__ unsigned int packbf(float lo, float hi) {
    float2 f2; f2.x = lo; f2.y = hi;
    __hip_bfloat162 h2 = __float22bfloat162_rn(f2);
    unsigned int u;
    __builtin_memcpy(&u, &h2, 4);
    return u;
}
// raw v_exp_f32 (log2 domain; args <= 0, flush-to-zero is fine for softmax)
#define EXP2R __builtin_amdgcn_exp2f
// async global->LDS, 16B per lane; LDS dest = wave-uniform base + lane*16
static __device__ __forceinline__ void async_copy16(void* lds, const void* g) {
    __builtin_amdgcn_global_load_lds(
        (const __attribute__((address_space(1))) unsigned char*)g,
        (__attribute__((address_space(3))) unsigned char*)lds, 16, 0, 0);
}

union bfrag {
    unsigned int u[4];
    short8v v;
};

// ---------------- Kernel 0: W f32 -> bf16, concat [q|k|v] rows -------------
__global__ __launch_bounds__(256) void wcvt_kernel(
    const float* __restrict__ Wq, const float* __restrict__ Wk,
    const float* __restrict__ Wv, unsigned short* __restrict__ wb)
{
    const int idx = blockIdx.x * 256 + threadIdx.x;   // 12288 threads x 8 elems
    const int e   = idx << 3;
    const int row = e >> 9, col = e & 511;
    const float* src = (row < 64) ? Wq : (row < 128) ? Wk : Wv;
    const float* p = src + (size_t)(row & 63) * DIMC + col;
    float4 a = *(const float4*)p;
    float4 b = *(const float4*)(p + 4);
    uint4 o;
    o.x = packbf(a.x, a.y); o.y = packbf(a.z, a.w);
    o.z = packbf(b.x, b.y); o.w = packbf(b.z, b.w);
    *(uint4*)(wb + e) = o;
}

// ---------------- Kernel A: MFMA QKV projection + rotary, LDS-staged --------
// Round 9: rebuilt on the attn staging skeleton (global_load_lds + dbuf +
// one barrier/iter) -- r8 showed naked flat loads are latency-capped at
// ~10 resident waves/CU regardless of grid size.
// Block = 4 waves x 256 thr, t-tile 64 (grid 512). Wave w owns h-tiles
// {3w,3w+1,3w+2} (16 h-rows each). K-loop: 16 iters of 32.
//   x chunk [64 t][32 k] f32 staged to LDS (8KB, dbuf); per-wave rows
//   16w..16w+15, 2 calls/iter; source pre-swizzled cb = (l&7)^(l>>3&7),
//   read slot (2g+e)^(q&7)  -- same involution family attn verified.
//   W loads direct global->reg (L2-resident; 3/iter, issued at iter head).
// Per iter/wave: 12 MFMA + 8 b128 LDS reads + 16 cvt_pk.
__global__ __launch_bounds__(256, 2) void qkv_mfma_kernel(
    const float* __restrict__ x,
    const unsigned short* __restrict__ wb,
    const float* __restrict__ fxr, const float* __restrict__ fxi,
    const float* __restrict__ fyr, const float* __restrict__ fyi,
    unsigned short* __restrict__ qo, unsigned short* __restrict__ ko,
    unsigned short* __restrict__ vt)
{
    __shared__ unsigned char xlds[16384];     // [2][64][32] f32, dbuf

    const int tid = threadIdx.x;
    const int w   = tid >> 6;                 // wave -> h-tile triple
    const int l   = tid & 63;
    const int q   = l & 15;
    const int g   = l >> 4;
    const int t0  = blockIdx.x << 6;          // 64 t-rows per block

    f32x4 acc[3][4];
    #pragma unroll
    for (int j = 0; j < 3; ++j)
        #pragma unroll
        for (int tt = 0; tt < 4; ++tt) acc[j][tt] = (f32x4){0.f, 0.f, 0.f, 0.f};

    // W row pointers for this wave's 3 h-tiles
    const unsigned short* wp0 = wb + ((size_t)((3 * w + 0) * 16 + q)) * DIMC + 8 * g;
    const unsigned short* wp1 = wb + ((size_t)((3 * w + 1) * 16 + q)) * DIMC + 8 * g;
    const unsigned short* wp2 = wb + ((size_t)((3 * w + 2) * 16 + q)) * DIMC + 8 * g;

    // staging lane constants (per-lane pre-swizzled source)
    const int rl = l >> 3;                    // 0..7 row-in-call
    const int cb = (l & 7) ^ rl;              // source col-block (involution)
    const float* xsrc0 = x + (size_t)(t0 + 16 * w + 0 + rl) * DIMC + 4 * cb;
    const float* xsrc1 = x + (size_t)(t0 + 16 * w + 8 + rl) * DIMC + 4 * cb;
    unsigned char* xdst0 = xlds + (16 * w + 0) * 128;   // wave-uniform bases
    unsigned char* xdst1 = xlds + (16 * w + 8) * 128;

#define STAGE_X(bufsel, k0) do {                                              \
        async_copy16(xdst0 + (bufsel) * 8192, xsrc0 + (k0));                  \
        async_copy16(xdst1 + (bufsel) * 8192, xsrc1 + (k0));                  \
    } while (0)

    STAGE_X(0, 0);
    __syncthreads();

    int cur = 0;
    for (int it = 0; it < 16; ++it) {
        const int k0 = it << 5;
        if (it < 15) STAGE_X(cur ^ 1, k0 + 32);

        // W fragments for this k-chunk (L2 hits, issued before LDS reads)
        short8v wf0 = *(const short8v*)(wp0 + k0);
        short8v wf1 = *(const short8v*)(wp1 + k0);
        short8v wf2 = *(const short8v*)(wp2 + k0);

        const unsigned char* xb = xlds + cur * 8192;
        #pragma unroll
        for (int tt = 0; tt < 4; ++tt) {
            const int rr = tt * 16 + q;
            const int s0 = (2 * g)     ^ (q & 7);
            const int s1 = (2 * g + 1) ^ (q & 7);
            float4 f0 = *(const float4*)(xb + rr * 128 + s0 * 16);
            float4 f1 = *(const float4*)(xb + rr * 128 + s1 * 16);
            bfrag xv;
            xv.u[0] = packbf(f0.x, f0.y); xv.u[1] = packbf(f0.z, f0.w);
            xv.u[2] = packbf(f1.x, f1.y); xv.u[3] = packbf(f1.z, f1.w);
            acc[0][tt] = __builtin_amdgcn_mfma_f32_16x16x32_bf16(wf0, xv.v, acc[0][tt], 0, 0, 0);
            acc[1][tt] = __builtin_amdgcn_mfma_f32_16x16x32_bf16(wf1, xv.v, acc[1][tt], 0, 0, 0);
            acc[2][tt] = __builtin_amdgcn_mfma_f32_16x16x32_bf16(wf2, xv.v, acc[2][tt], 0, 0, 0);
        }

        __syncthreads();                      // nxt resident; cur reads done
        cur ^= 1;
    }

    // ---- epilogue: per h-tile uniform q/k/v branch; rotary in-lane ----
    const float qscale = 1.4426950408889634f / 22.627416997969522f; // log2e/sqrt(512)
    #pragma unroll
    for (int j = 0; j < 3; ++j) {
        const int gt   = 3 * w + j;           // global h-tile 0..11
        const int mat  = gt >> 2;             // 0=q, 1=k, 2=v
        const int hbase = (gt & 3) * 16 + 4 * g;
        #pragma unroll
        for (int tt = 0; tt < 4; ++tt) {
            const int trow = t0 + tt * 16 + q;
            const int tl   = trow & (TT - 1);
            if (mat == 2) {
                const int b = trow >> 11;
                #pragma unroll
                for (int r = 0; r < 4; ++r)
                    vt[((size_t)(b * HEADH) + hbase + r) * TT + tl] = f2bf(acc[j][tt][r]);
            } else {
                const float sc = (mat == 0) ? qscale : 1.f;
                unsigned short* dst = ((mat == 0) ? qo : ko) + (size_t)trow * HEADH;
                const int half = hbase >> 5;
                const float* frt = half ? fyr : fxr;
                const float* fit = half ? fyi : fxi;
                const int pi0 = (hbase & 31) >> 1;
                float fr0 = frt[tl * 16 + pi0],     fi0 = fit[tl * 16 + pi0];
                float fr1 = frt[tl * 16 + pi0 + 1], fi1 = fit[tl * 16 + pi0 + 1];
                float e0 = acc[j][tt][0] * fr0 - acc[j][tt][1] * fi0;
                float e1 = acc[j][tt][0] * fi0 + acc[j][tt][1] * fr0;
                float e2 = acc[j][tt][2] * fr1 - acc[j][tt][3] * fi1;
                float e3 = acc[j][tt][2] * fi1 + acc[j][tt][3] * fr1;
                uint2 ow;
                ow.x = packbf(e0 * sc, e1 * sc);
                ow.y = packbf(e2 * sc, e3 * sc);
                *(uint2*)(dst + hbase) = ow;
            }
        }
    }
#undef STAGE_X
}

// ---------------- Kernel B: MFMA flash attention (unchanged from r8) --------
__global__ __launch_bounds__(256, 2) void attn_mfma_kernel(
    const unsigned short* __restrict__ qws,   // [b][t][64] bf16, pre-scaled
    const unsigned short* __restrict__ kws,   // [b][t][64] bf16
    const unsigned short* __restrict__ vtw,   // [b][d][t]  bf16 (V^T)
    float* __restrict__ out)
{
    __shared__ unsigned char smem[40960];     // K dbuf 16K | V dbuf 16K | plds 8K

    const int tid = threadIdx.x;
    const int w   = tid >> 6;                 // wave -> q-subtile
    const int l   = tid & 63;
    const int q   = l & 15;
    const int g   = l >> 4;
    const int b   = blockIdx.x >> 5;
    const int q0  = (blockIdx.x & 31) << 6;   // 64 q-rows per block
    const int qw  = q0 + 16 * w;              // this wave's q base
    const int rx  = q & 7;                    // read-side swizzle
    const int swz = (q & 7) << 2;             // plds swizzle (verified r2-r8)

    const int rl = l >> 3;
    const int sl = (l & 7) ^ rl;              // involution pre-swizzle

    unsigned int* pldsw = (unsigned int*)(smem + 32768 + (w << 11));

    const unsigned short* kbase = kws + (size_t)b * TT * HEADH;
    const unsigned short* vbase = vtw + (size_t)b * HEADH * TT;

    const unsigned short* ksrc0 = kbase + (size_t)(16 * w + rl) * HEADH + 8 * sl;
    const unsigned short* ksrc1 = kbase + (size_t)(16 * w + 8 + rl) * HEADH + 8 * sl;
    const unsigned short* vsrc0 = vbase + (size_t)(16 * w + rl) * TT + 8 * sl;
    const unsigned short* vsrc1 = vbase + (size_t)(16 * w + 8 + rl) * TT + 8 * sl;

#define STAGE_TILE(bufsel, kv)  do {                                          \
        unsigned char* kd = smem + (bufsel) * 8192 + (w << 11);               \
        unsigned char* vd = smem + 16384 + (bufsel) * 8192 + (w << 11);       \
        async_copy16(kd,        ksrc0 + (size_t)(kv) * HEADH);                \
        async_copy16(kd + 1024, ksrc1 + (size_t)(kv) * HEADH);                \
        async_copy16(vd,        vsrc0 + (kv));                                \
        async_copy16(vd + 1024, vsrc1 + (kv));                                \
    } while (0)

    short8v qf0, qf1;
    {
        const unsigned short* qp = qws + ((size_t)(b * TT + qw + q)) * HEADH + 8 * g;
        qf0 = *(const short8v*)(qp);
        qf1 = *(const short8v*)(qp + 32);
    }

    f32x4 oacc[4];
    #pragma unroll
    for (int mt = 0; mt < 4; ++mt) oacc[mt] = (f32x4){0.f, 0.f, 0.f, 0.f};
    float m = -1e30f, lsum = 0.f;

    STAGE_TILE(0, 0);
    __syncthreads();                          // tile 0 resident

    int cur = 0;
    for (int it = 0; it < 32; ++it) {
        if (it < 31) STAGE_TILE(cur ^ 1, (it + 1) << 6);

        const unsigned char* kb = smem + cur * 8192;
        const unsigned char* vb = smem + 16384 + cur * 8192;

        // ---- QK^T from LDS ----
        f32x4 sacc[4];
        #pragma unroll
        for (int n = 0; n < 4; ++n) {
            const int r = 16 * n + q;
            const short8v k0 = *(const short8v*)(kb + r * 128 + ((g ^ rx) << 4));
            const short8v k1 = *(const short8v*)(kb + r * 128 + (((4 + g) ^ rx) << 4));
            f32x4 z = (f32x4){0.f, 0.f, 0.f, 0.f};
            z = __builtin_amdgcn_mfma_f32_16x16x32_bf16(k0, qf0, z, 0, 0, 0);
            z = __builtin_amdgcn_mfma_f32_16x16x32_bf16(k1, qf1, z, 0, 0, 0);
            sacc[n] = z;
        }

        // ---- online softmax (lane owns q-row qw + (l&15)) ----
        float cmax = sacc[0][0];
        #pragma unroll
        for (int n = 0; n < 4; ++n)
            #pragma unroll
            for (int r = 0; r < 4; ++r) cmax = fmaxf(cmax, sacc[n][r]);
        cmax = fmaxf(cmax, __shfl_xor(cmax, 16));
        cmax = fmaxf(cmax, __shfl_xor(cmax, 32));
        const float mnew = fmaxf(m, cmax);

        float p[4][4];
        float psum = 0.f;
        #pragma unroll
        for (int n = 0; n < 4; ++n)
            #pragma unroll
            for (int r = 0; r < 4; ++r) {
                p[n][r] = EXP2R(sacc[n][r] - mnew);   // raw v_exp_f32
                psum += p[n][r];
            }
        psum += __shfl_xor(psum, 16);
        psum += __shfl_xor(psum, 32);

        const float sc = EXP2R(m - mnew);
        if (__any(cmax > m)) {
            #pragma unroll
            for (int mt = 0; mt < 4; ++mt)
                #pragma unroll
                for (int r = 0; r < 4; ++r) oacc[mt][r] *= sc;
        }
        lsum = lsum * sc + psum;
        m = mnew;

        // ---- P^T -> bf16 -> per-wave swizzled LDS ----
        #pragma unroll
        for (int n = 0; n < 4; ++n) {
            uint2 wv;
            wv.x = packbf(p[n][0], p[n][1]);
            wv.y = packbf(p[n][2], p[n][3]);
            *(uint2*)&pldsw[q * 32 + ((8 * n + 2 * g) ^ swz)] = wv;
        }

        // ---- PV: out^T += V^T . P^T (V from LDS) ----
        #pragma unroll
        for (int s = 0; s < 2; ++s) {
            const short8v pb = *(const short8v*)&pldsw[q * 32 + ((16 * s + 4 * g) ^ swz)];
            #pragma unroll
            for (int mt = 0; mt < 4; ++mt) {
                const int d = 16 * mt + q;
                const short8v vfr = *(const short8v*)(vb + d * 128 + ((((s << 2) + g) ^ rx) << 4));
                oacc[mt] = __builtin_amdgcn_mfma_f32_16x16x32_bf16(vfr, pb, oacc[mt], 0, 0, 0);
            }
        }

        __syncthreads();                      // nxt resident; cur reads done
        cur ^= 1;
    }

    // ---- normalize + store: oacc[mt][r] = out[qw+q][16mt+4g+r] ----
    const float inv = 1.f / lsum;
    float* op = out + ((size_t)(b * TT + qw + q)) * HEADH;
    #pragma unroll
    for (int mt = 0; mt < 4; ++mt) {
        float4 v4 = make_float4(oacc[mt][0] * inv, oacc[mt][1] * inv,
                                oacc[mt][2] * inv, oacc[mt][3] * inv);
        *(float4*)(op + 16 * mt + 4 * g) = v4;
    }
#undef STAGE_TILE
}

extern "C" void kernel_launch(void* const* d_in, const int* in_sizes, int n_in,
                              void* d_out, int out_size, void* d_ws, size_t ws_size,
                              hipStream_t stream)
{
    const float* x   = (const float*)d_in[0];
    const float* Wq  = (const float*)d_in[1];
    const float* Wk  = (const float*)d_in[2];
    const float* Wv  = (const float*)d_in[3];
    const float* fxr = (const float*)d_in[4];
    const float* fxi = (const float*)d_in[5];
    const float* fyr = (const float*)d_in[6];
    const float* fyi = (const float*)d_in[7];
    float* out = (float*)d_out;

    unsigned short* qo = (unsigned short*)d_ws;                  // 4 MB
    unsigned short* ko = qo + (size_t)BB * TT * HEADH;           // 4 MB
    unsigned short* vt = ko + (size_t)BB * TT * HEADH;           // 4 MB
    unsigned short* wb = vt + (size_t)BB * TT * HEADH;           // 192 KB

    wcvt_kernel<<<48, 256, 0, stream>>>(Wq, Wk, Wv, wb);
    qkv_mfma_kernel<<<(BB * TT) / 64, 256, 0, stream>>>(x, wb, fxr, fxi, fyr, fyi,
                                                        qo, ko, vt);
    attn_mfma_kernel<<<BB * 32, 256, 0, stream>>>(qo, ko, vt, out);
}